// Round 4
// baseline (30.068 us; speedup 1.0000x reference)
//
#include <hip/hip_runtime.h>

// Problem constants (match reference)
#define BB 64
#define HH 480
#define WW 640
#define PP 8192
#define IMG (HH * WW)            // 307200 floats per image
#define CHUNKS 16                // blocks per batch
#define TPB 256
#define GRID (BB * CHUNKS)       // 1024 blocks -> 4 blocks/CU (all co-resident)
#define IMG4 (IMG / 4)           // 76800 float4 per image
#define PSTRIDE (CHUNKS * TPB)   // 4096 prefetch threads per image

// Block mapping: b = bid & 63, c = bid >> 6.
// XCD(bid) = bid % 8 = b % 8 -> all 16 chunk-blocks of batch b land on one XCD,
// which also prefetches image b -> gathers hit local L2 / shared L3.

__global__ __launch_bounds__(TPB) void rdl_partial(
    const float* __restrict__ depth,   // [B, H*W]
    const int*  __restrict__ xA,
    const int*  __restrict__ yA,
    const int*  __restrict__ xB,
    const int*  __restrict__ yB,
    const int*  __restrict__ rel,
    float4*     __restrict__ ws)       // [GRID] partials {s_log, s_sq, n_log, n_sq}
{
    const int bid = blockIdx.x;
    const int b   = bid & (BB - 1);    // batch
    const int c   = bid >> 6;          // chunk 0..15
    const int tid = threadIdx.x;
    const int pair0 = b * PP + c * (PP / CHUNKS) + tid * 2;

    // --- issue coalesced index loads first (latency hides under prefetch) ---
    const int2 xa2 = *reinterpret_cast<const int2*>(xA  + pair0);
    const int2 ya2 = *reinterpret_cast<const int2*>(yA  + pair0);
    const int2 xb2 = *reinterpret_cast<const int2*>(xB  + pair0);
    const int2 yb2 = *reinterpret_cast<const int2*>(yB  + pair0);
    const int2 rr2 = *reinterpret_cast<const int2*>(rel + pair0);

    const float*  img  = depth + (size_t)b * IMG;
    const float4* imgv = reinterpret_cast<const float4*>(img);

    // --- phase 1: coalesced streaming prefetch of image b (warm L2/L3) ---
    // 16 blocks x 256 threads cover IMG4=76800 float4 at stride 4096.
    {
        int i = c * TPB + tid;
#pragma unroll 1
        for (int g = 0; g < 4; ++g) {  // 4 groups of 4 in-flight loads = 16
            const float4 a0 = imgv[i];
            const float4 a1 = imgv[i +     PSTRIDE];
            const float4 a2 = imgv[i + 2 * PSTRIDE];
            const float4 a3 = imgv[i + 3 * PSTRIDE];
            asm volatile("" ::
                "v"(a0.x), "v"(a0.y), "v"(a0.z), "v"(a0.w),
                "v"(a1.x), "v"(a1.y), "v"(a1.z), "v"(a1.w),
                "v"(a2.x), "v"(a2.y), "v"(a2.z), "v"(a2.w),
                "v"(a3.x), "v"(a3.y), "v"(a3.z), "v"(a3.w));
            i += 4 * PSTRIDE;
        }
        // tail: 2-3 more loads per thread (76800 = 18.75 * 4096)
#pragma unroll 1
        for (; i < IMG4; i += PSTRIDE) {
            const float4 a = imgv[i];
            asm volatile("" :: "v"(a.x), "v"(a.y), "v"(a.z), "v"(a.w));
        }
    }
    __syncthreads();   // phase alignment (grid is fully co-resident)

    // --- phase 2: gathers (now L2/L3-resident) ---
    const int xas[2] = {xa2.x, xa2.y};
    const int yas[2] = {ya2.x, ya2.y};
    const int xbs[2] = {xb2.x, xb2.y};
    const int ybs[2] = {yb2.x, yb2.y};
    const int rs [2] = {rr2.x, rr2.y};

    float zA[2], zB[2];
#pragma unroll
    for (int k = 0; k < 2; ++k) {
        zA[k] = img[xas[k] * WW + yas[k]];
        zB[k] = img[xbs[k] * WW + ybs[k]];
    }

    float s_log = 0.f, s_sq = 0.f;
    int   n_log = 0,   n_sq = 0;
#pragma unroll
    for (int k = 0; k < 2; ++k) {
        const float pred = zA[k] - zB[k];
        const int r = rs[k];
        if (r != 2) {
            if (r == 0) {
                s_sq += pred * pred;
                n_sq++;
            } else {
                const float x = -(float)r * pred;
                // stable softplus: max(x,0) + log1p(exp(-|x|))
                s_log += fmaxf(x, 0.f) + log1pf(expf(-fabsf(x)));
                n_log++;
            }
        }
    }

    // 64-lane wave reduction
#pragma unroll
    for (int off = 32; off > 0; off >>= 1) {
        s_log += __shfl_down(s_log, off);
        s_sq  += __shfl_down(s_sq,  off);
        n_log += __shfl_down(n_log, off);
        n_sq  += __shfl_down(n_sq,  off);
    }

    __shared__ float4 lds[TPB / 64];
    const int wave = tid >> 6;
    if ((tid & 63) == 0)
        lds[wave] = make_float4(s_log, s_sq, (float)n_log, (float)n_sq);
    __syncthreads();

    if (tid == 0) {
        float4 acc = lds[0];
#pragma unroll
        for (int wv = 1; wv < TPB / 64; ++wv) {
            acc.x += lds[wv].x;
            acc.y += lds[wv].y;
            acc.z += lds[wv].z;
            acc.w += lds[wv].w;
        }
        ws[bid] = acc;   // layout: ws[c*64 + b]
    }
}

__global__ __launch_bounds__(TPB) void rdl_final(
    const float4* __restrict__ ws,     // [GRID] partials, index = c*64 + b
    float*        __restrict__ out)
{
    const int tid   = threadIdx.x;     // 256 threads
    const int batch = tid >> 2;        // 0..63
    const int sub   = tid & 3;         // 4 threads per batch
    float sl = 0.f, ss = 0.f, nl = 0.f, ns = 0.f;
#pragma unroll
    for (int k = 0; k < CHUNKS / 4; ++k) {
        const int chunk = sub * (CHUNKS / 4) + k;
        const float4 v = ws[chunk * BB + batch];
        sl += v.x; ss += v.y; nl += v.z; ns += v.w;
    }
    // combine the 4 sub-threads of each batch (contiguous lanes, same wave)
#pragma unroll
    for (int off = 1; off < 4; off <<= 1) {
        sl += __shfl_xor(sl, off);
        ss += __shfl_xor(ss, off);
        nl += __shfl_xor(nl, off);
        ns += __shfl_xor(ns, off);
    }
    __shared__ float lossArr[BB];
    if (sub == 0)
        lossArr[batch] = sl / nl + ss / ns;   // per-batch log_loss + sq_loss
    __syncthreads();
    if (tid < BB) {                    // wave 0
        float loss = lossArr[tid];
#pragma unroll
        for (int off = 32; off > 0; off >>= 1)
            loss += __shfl_down(loss, off);
        if (tid == 0)
            out[0] = loss * (1.0f / (float)BB);
    }
}

extern "C" void kernel_launch(void* const* d_in, const int* in_sizes, int n_in,
                              void* d_out, int out_size, void* d_ws, size_t ws_size,
                              hipStream_t stream) {
    const float* depth = (const float*)d_in[0];
    const int*   xA    = (const int*)d_in[1];
    const int*   yA    = (const int*)d_in[2];
    const int*   xB    = (const int*)d_in[3];
    const int*   yB    = (const int*)d_in[4];
    const int*   rel   = (const int*)d_in[5];
    float*       out   = (float*)d_out;
    float4*      ws    = (float4*)d_ws;   // GRID*16 B = 16 KiB

    rdl_partial<<<GRID, TPB, 0, stream>>>(depth, xA, yA, xB, yB, rel, ws);
    rdl_final<<<1, TPB, 0, stream>>>(ws, out);
}

// Round 5
// 21.594 us; speedup vs baseline: 1.3924x; 1.3924x over previous
//
#include <hip/hip_runtime.h>

// Problem constants (match reference)
#define BB 64
#define HH 480
#define WW 640
#define PP 8192
#define CHUNKS 16          // blocks per batch; PP/CHUNKS = 512 = TPB*2 -> 2 pairs/thread
#define TPB 256
#define GRID (BB * CHUNKS) // 1024 blocks -> 4 blocks/CU -> 16 waves/CU

// Block mapping: b = bid & 63, c = bid >> 6.
// XCD(bid) = bid % 8 = b % 8 -> all 16 chunk-blocks of batch b land on ONE XCD:
// image b's gather lines are fetched into exactly one L2 (no cross-XCD
// duplicate fetches), and within-image line reuse (~1.5 touches/line) is
// captured by that L2 (distinct working set ~705 KB/image << 4 MiB).

__global__ __launch_bounds__(TPB) void rdl_partial(
    const float* __restrict__ depth,   // [B, H*W]
    const int*  __restrict__ xA,
    const int*  __restrict__ yA,
    const int*  __restrict__ xB,
    const int*  __restrict__ yB,
    const int*  __restrict__ rel,
    float4*     __restrict__ ws)       // [GRID] partials {s_log, s_sq, n_log, n_sq}
{
    const int bid = blockIdx.x;
    const int b   = bid & (BB - 1);    // batch (pins batch -> XCD)
    const int c   = bid >> 6;          // chunk 0..15
    const int tid = threadIdx.x;
    const int pair0 = b * PP + c * (PP / CHUNKS) + tid * 2;

    // Coalesced vector index loads
    const int2 xa2 = *reinterpret_cast<const int2*>(xA  + pair0);
    const int2 ya2 = *reinterpret_cast<const int2*>(yA  + pair0);
    const int2 xb2 = *reinterpret_cast<const int2*>(xB  + pair0);
    const int2 yb2 = *reinterpret_cast<const int2*>(yB  + pair0);
    const int2 rr2 = *reinterpret_cast<const int2*>(rel + pair0);

    const int xas[2] = {xa2.x, xa2.y};
    const int yas[2] = {ya2.x, ya2.y};
    const int xbs[2] = {xb2.x, xb2.y};
    const int ybs[2] = {yb2.x, yb2.y};
    const int rs [2] = {rr2.x, rr2.y};

    const float* __restrict__ img = depth + (size_t)b * (HH * WW);

    // Issue all 4 gathers up front (independent -> 4 outstanding VMEM ops)
    float zA[2], zB[2];
#pragma unroll
    for (int k = 0; k < 2; ++k) {
        zA[k] = img[xas[k] * WW + yas[k]];
        zB[k] = img[xbs[k] * WW + ybs[k]];
    }

    float s_log = 0.f, s_sq = 0.f;
    int   n_log = 0,   n_sq = 0;
#pragma unroll
    for (int k = 0; k < 2; ++k) {
        const float pred = zA[k] - zB[k];
        const int r = rs[k];
        if (r != 2) {
            if (r == 0) {
                s_sq += pred * pred;
                n_sq++;
            } else {
                const float x = -(float)r * pred;
                // stable softplus: max(x,0) + log1p(exp(-|x|))
                s_log += fmaxf(x, 0.f) + log1pf(expf(-fabsf(x)));
                n_log++;
            }
        }
    }

    // 64-lane wave reduction
#pragma unroll
    for (int off = 32; off > 0; off >>= 1) {
        s_log += __shfl_down(s_log, off);
        s_sq  += __shfl_down(s_sq,  off);
        n_log += __shfl_down(n_log, off);
        n_sq  += __shfl_down(n_sq,  off);
    }

    __shared__ float4 lds[TPB / 64];
    const int wave = tid >> 6;
    if ((tid & 63) == 0)
        lds[wave] = make_float4(s_log, s_sq, (float)n_log, (float)n_sq);
    __syncthreads();

    if (tid == 0) {
        float4 acc = lds[0];
#pragma unroll
        for (int wv = 1; wv < TPB / 64; ++wv) {
            acc.x += lds[wv].x;
            acc.y += lds[wv].y;
            acc.z += lds[wv].z;
            acc.w += lds[wv].w;
        }
        ws[bid] = acc;   // index = c*64 + b
    }
}

__global__ __launch_bounds__(TPB) void rdl_final(
    const float4* __restrict__ ws,     // [GRID] partials, index = c*64 + b
    float*        __restrict__ out)
{
    const int tid   = threadIdx.x;     // 256 threads
    const int batch = tid >> 2;        // 0..63
    const int sub   = tid & 3;         // 4 threads per batch
    float sl = 0.f, ss = 0.f, nl = 0.f, ns = 0.f;
#pragma unroll
    for (int k = 0; k < CHUNKS / 4; ++k) {
        const int chunk = sub * (CHUNKS / 4) + k;
        const float4 v = ws[chunk * BB + batch];
        sl += v.x; ss += v.y; nl += v.z; ns += v.w;
    }
    // combine the 4 sub-threads of each batch (contiguous lanes, same wave)
#pragma unroll
    for (int off = 1; off < 4; off <<= 1) {
        sl += __shfl_xor(sl, off);
        ss += __shfl_xor(ss, off);
        nl += __shfl_xor(nl, off);
        ns += __shfl_xor(ns, off);
    }
    __shared__ float lossArr[BB];
    if (sub == 0)
        lossArr[batch] = sl / nl + ss / ns;   // per-batch log_loss + sq_loss
    __syncthreads();
    if (tid < BB) {                    // wave 0
        float loss = lossArr[tid];
#pragma unroll
        for (int off = 32; off > 0; off >>= 1)
            loss += __shfl_down(loss, off);
        if (tid == 0)
            out[0] = loss * (1.0f / (float)BB);
    }
}

extern "C" void kernel_launch(void* const* d_in, const int* in_sizes, int n_in,
                              void* d_out, int out_size, void* d_ws, size_t ws_size,
                              hipStream_t stream) {
    const float* depth = (const float*)d_in[0];
    const int*   xA    = (const int*)d_in[1];
    const int*   yA    = (const int*)d_in[2];
    const int*   xB    = (const int*)d_in[3];
    const int*   yB    = (const int*)d_in[4];
    const int*   rel   = (const int*)d_in[5];
    float*       out   = (float*)d_out;
    float4*      ws    = (float4*)d_ws;   // GRID*16 B = 16 KiB

    rdl_partial<<<GRID, TPB, 0, stream>>>(depth, xA, yA, xB, yB, rel, ws);
    rdl_final<<<1, TPB, 0, stream>>>(ws, out);
}

// Round 7
// 21.387 us; speedup vs baseline: 1.4059x; 1.0096x over previous
//
#include <hip/hip_runtime.h>

// Problem constants (match reference)
#define BB 64
#define HH 480
#define WW 640
#define PP 8192
#define CHUNKS 16          // blocks per batch; PP/CHUNKS = 512 = TPB*2 -> 2 pairs/thread
#define TPB 256
#define GRID (BB * CHUNKS) // 1024 blocks -> 4 blocks/CU -> 16 waves/CU

// Native clang vector type (accepted by __builtin_nontemporal_load,
// unlike HIP's struct-wrapped int2)
typedef int v2i __attribute__((ext_vector_type(2)));

// Block mapping: b = bid & 63, c = bid >> 6.
// XCD(bid) = bid % 8 = b % 8 -> all 16 chunk-blocks of batch b land on ONE XCD:
// image b's gather lines are fetched into exactly one L2 (no cross-XCD
// duplicate fetches); within-image line reuse (~1.5 touches/line) is captured
// by that L2 + L3. Index streams are nontemporal: zero reuse, keep them out
// of the 4 MiB L2 whose capacity the gather set (5.6 MB/XCD) already exceeds.

__global__ __launch_bounds__(TPB) void rdl_partial(
    const float* __restrict__ depth,   // [B, H*W]
    const int*  __restrict__ xA,
    const int*  __restrict__ yA,
    const int*  __restrict__ xB,
    const int*  __restrict__ yB,
    const int*  __restrict__ rel,
    float4*     __restrict__ ws)       // [GRID] partials {s_log, s_sq, n_log, n_sq}
{
    const int bid = blockIdx.x;
    const int b   = bid & (BB - 1);    // batch (pins batch -> XCD)
    const int c   = bid >> 6;          // chunk 0..15
    const int tid = threadIdx.x;
    const int pair0 = b * PP + c * (PP / CHUNKS) + tid * 2;

    // Coalesced, nontemporal vector index loads (streaming, no reuse)
    const v2i xa2 = __builtin_nontemporal_load(reinterpret_cast<const v2i*>(xA  + pair0));
    const v2i ya2 = __builtin_nontemporal_load(reinterpret_cast<const v2i*>(yA  + pair0));
    const v2i xb2 = __builtin_nontemporal_load(reinterpret_cast<const v2i*>(xB  + pair0));
    const v2i yb2 = __builtin_nontemporal_load(reinterpret_cast<const v2i*>(yB  + pair0));
    const v2i rr2 = __builtin_nontemporal_load(reinterpret_cast<const v2i*>(rel + pair0));

    const int xas[2] = {xa2.x, xa2.y};
    const int yas[2] = {ya2.x, ya2.y};
    const int xbs[2] = {xb2.x, xb2.y};
    const int ybs[2] = {yb2.x, yb2.y};
    const int rs [2] = {rr2.x, rr2.y};

    const float* __restrict__ img = depth + (size_t)b * (HH * WW);

    // Issue all 4 gathers up front (independent -> 4 outstanding VMEM ops)
    float zA[2], zB[2];
#pragma unroll
    for (int k = 0; k < 2; ++k) {
        zA[k] = img[xas[k] * WW + yas[k]];
        zB[k] = img[xbs[k] * WW + ybs[k]];
    }

    float s_log = 0.f, s_sq = 0.f;
    int   n_log = 0,   n_sq = 0;
#pragma unroll
    for (int k = 0; k < 2; ++k) {
        const float pred = zA[k] - zB[k];
        const int r = rs[k];
        if (r != 2) {
            if (r == 0) {
                s_sq += pred * pred;
                n_sq++;
            } else {
                const float x = -(float)r * pred;
                // stable softplus: max(x,0) + log1p(exp(-|x|))
                s_log += fmaxf(x, 0.f) + log1pf(expf(-fabsf(x)));
                n_log++;
            }
        }
    }

    // 64-lane wave reduction
#pragma unroll
    for (int off = 32; off > 0; off >>= 1) {
        s_log += __shfl_down(s_log, off);
        s_sq  += __shfl_down(s_sq,  off);
        n_log += __shfl_down(n_log, off);
        n_sq  += __shfl_down(n_sq,  off);
    }

    __shared__ float4 lds[TPB / 64];
    const int wave = tid >> 6;
    if ((tid & 63) == 0)
        lds[wave] = make_float4(s_log, s_sq, (float)n_log, (float)n_sq);
    __syncthreads();

    if (tid == 0) {
        float4 acc = lds[0];
#pragma unroll
        for (int wv = 1; wv < TPB / 64; ++wv) {
            acc.x += lds[wv].x;
            acc.y += lds[wv].y;
            acc.z += lds[wv].z;
            acc.w += lds[wv].w;
        }
        ws[bid] = acc;   // index = c*64 + b
    }
}

__global__ __launch_bounds__(TPB) void rdl_final(
    const float4* __restrict__ ws,     // [GRID] partials, index = c*64 + b
    float*        __restrict__ out)
{
    const int tid   = threadIdx.x;     // 256 threads
    const int batch = tid >> 2;        // 0..63
    const int sub   = tid & 3;         // 4 threads per batch
    float sl = 0.f, ss = 0.f, nl = 0.f, ns = 0.f;
#pragma unroll
    for (int k = 0; k < CHUNKS / 4; ++k) {
        const int chunk = sub * (CHUNKS / 4) + k;
        const float4 v = ws[chunk * BB + batch];
        sl += v.x; ss += v.y; nl += v.z; ns += v.w;
    }
    // combine the 4 sub-threads of each batch (contiguous lanes, same wave)
#pragma unroll
    for (int off = 1; off < 4; off <<= 1) {
        sl += __shfl_xor(sl, off);
        ss += __shfl_xor(ss, off);
        nl += __shfl_xor(nl, off);
        ns += __shfl_xor(ns, off);
    }
    __shared__ float lossArr[BB];
    if (sub == 0)
        lossArr[batch] = sl / nl + ss / ns;   // per-batch log_loss + sq_loss
    __syncthreads();
    if (tid < BB) {                    // wave 0
        float loss = lossArr[tid];
#pragma unroll
        for (int off = 32; off > 0; off >>= 1)
            loss += __shfl_down(loss, off);
        if (tid == 0)
            out[0] = loss * (1.0f / (float)BB);
    }
}

extern "C" void kernel_launch(void* const* d_in, const int* in_sizes, int n_in,
                              void* d_out, int out_size, void* d_ws, size_t ws_size,
                              hipStream_t stream) {
    const float* depth = (const float*)d_in[0];
    const int*   xA    = (const int*)d_in[1];
    const int*   yA    = (const int*)d_in[2];
    const int*   xB    = (const int*)d_in[3];
    const int*   yB    = (const int*)d_in[4];
    const int*   rel   = (const int*)d_in[5];
    float*       out   = (float*)d_out;
    float4*      ws    = (float4*)d_ws;   // GRID*16 B = 16 KiB

    rdl_partial<<<GRID, TPB, 0, stream>>>(depth, xA, yA, xB, yB, rel, ws);
    rdl_final<<<1, TPB, 0, stream>>>(ws, out);
}

// Round 8
// 18.750 us; speedup vs baseline: 1.6036x; 1.1406x over previous
//
#include <hip/hip_runtime.h>

// Problem constants (match reference)
#define BB 64
#define HH 480
#define WW 640
#define PP 8192
#define CHUNKS 16          // blocks per batch; PP/CHUNKS = 512 = TPB*2 -> 2 pairs/thread
#define TPB 256
#define GRID (BB * CHUNKS) // 1024 blocks -> 4 blocks/CU -> 16 waves/CU

// Native clang vector type (accepted by __builtin_nontemporal_load)
typedef int v2i __attribute__((ext_vector_type(2)));

// Block mapping: b = bid & 63, c = bid >> 6.
// XCD(bid) = bid % 8 = b % 8 -> all 16 chunk-blocks of batch b land on ONE XCD
// (no cross-XCD duplicate line fetches; ~1.5 touches/line reuse captured).
// Invalid pairs (r==2, 25% of all pairs) redirect their gather address to
// img[0] (one always-hot line) -> ~25% fewer random HBM line fetches, with
// straight-line code (v_cndmask on address, no divergence).

__global__ __launch_bounds__(TPB) void rdl_partial(
    const float* __restrict__ depth,   // [B, H*W]
    const int*  __restrict__ xA,
    const int*  __restrict__ yA,
    const int*  __restrict__ xB,
    const int*  __restrict__ yB,
    const int*  __restrict__ rel,
    float4*     __restrict__ ws)       // [GRID] partials {s_log, s_sq, n_log, n_sq}
{
    const int bid = blockIdx.x;
    const int b   = bid & (BB - 1);    // batch (pins batch -> XCD)
    const int c   = bid >> 6;          // chunk 0..15
    const int tid = threadIdx.x;
    const int pair0 = b * PP + c * (PP / CHUNKS) + tid * 2;

    // Coalesced, nontemporal vector index loads (streaming, no reuse)
    const v2i xa2 = __builtin_nontemporal_load(reinterpret_cast<const v2i*>(xA  + pair0));
    const v2i ya2 = __builtin_nontemporal_load(reinterpret_cast<const v2i*>(yA  + pair0));
    const v2i xb2 = __builtin_nontemporal_load(reinterpret_cast<const v2i*>(xB  + pair0));
    const v2i yb2 = __builtin_nontemporal_load(reinterpret_cast<const v2i*>(yB  + pair0));
    const v2i rr2 = __builtin_nontemporal_load(reinterpret_cast<const v2i*>(rel + pair0));

    const int xas[2] = {xa2.x, xa2.y};
    const int yas[2] = {ya2.x, ya2.y};
    const int xbs[2] = {xb2.x, xb2.y};
    const int ybs[2] = {yb2.x, yb2.y};
    const int rs [2] = {rr2.x, rr2.y};

    const float* __restrict__ img = depth + (size_t)b * (HH * WW);

    // Gathers: invalid pairs (r==2) load img[0] instead (hot line, no HBM fetch)
    float zA[2], zB[2];
#pragma unroll
    for (int k = 0; k < 2; ++k) {
        const bool valid = (rs[k] != 2);
        const int iA = valid ? (xas[k] * WW + yas[k]) : 0;
        const int iB = valid ? (xbs[k] * WW + ybs[k]) : 0;
        zA[k] = img[iA];
        zB[k] = img[iB];
    }

    float s_log = 0.f, s_sq = 0.f;
    int   n_log = 0,   n_sq = 0;
#pragma unroll
    for (int k = 0; k < 2; ++k) {
        const float pred = zA[k] - zB[k];
        const int r = rs[k];
        if (r != 2) {
            if (r == 0) {
                s_sq += pred * pred;
                n_sq++;
            } else {
                const float x = -(float)r * pred;
                // stable softplus: max(x,0) + log1p(exp(-|x|))
                s_log += fmaxf(x, 0.f) + log1pf(expf(-fabsf(x)));
                n_log++;
            }
        }
    }

    // 64-lane wave reduction
#pragma unroll
    for (int off = 32; off > 0; off >>= 1) {
        s_log += __shfl_down(s_log, off);
        s_sq  += __shfl_down(s_sq,  off);
        n_log += __shfl_down(n_log, off);
        n_sq  += __shfl_down(n_sq,  off);
    }

    __shared__ float4 lds[TPB / 64];
    const int wave = tid >> 6;
    if ((tid & 63) == 0)
        lds[wave] = make_float4(s_log, s_sq, (float)n_log, (float)n_sq);
    __syncthreads();

    if (tid == 0) {
        float4 acc = lds[0];
#pragma unroll
        for (int wv = 1; wv < TPB / 64; ++wv) {
            acc.x += lds[wv].x;
            acc.y += lds[wv].y;
            acc.z += lds[wv].z;
            acc.w += lds[wv].w;
        }
        ws[bid] = acc;   // index = c*64 + b
    }
}

__global__ __launch_bounds__(TPB) void rdl_final(
    const float4* __restrict__ ws,     // [GRID] partials, index = c*64 + b
    float*        __restrict__ out)
{
    const int tid   = threadIdx.x;     // 256 threads
    const int batch = tid >> 2;        // 0..63
    const int sub   = tid & 3;         // 4 threads per batch
    float sl = 0.f, ss = 0.f, nl = 0.f, ns = 0.f;
#pragma unroll
    for (int k = 0; k < CHUNKS / 4; ++k) {
        const int chunk = sub * (CHUNKS / 4) + k;
        const float4 v = ws[chunk * BB + batch];
        sl += v.x; ss += v.y; nl += v.z; ns += v.w;
    }
    // combine the 4 sub-threads of each batch (contiguous lanes, same wave)
#pragma unroll
    for (int off = 1; off < 4; off <<= 1) {
        sl += __shfl_xor(sl, off);
        ss += __shfl_xor(ss, off);
        nl += __shfl_xor(nl, off);
        ns += __shfl_xor(ns, off);
    }
    __shared__ float lossArr[BB];
    if (sub == 0)
        lossArr[batch] = sl / nl + ss / ns;   // per-batch log_loss + sq_loss
    __syncthreads();
    if (tid < BB) {                    // wave 0
        float loss = lossArr[tid];
#pragma unroll
        for (int off = 32; off > 0; off >>= 1)
            loss += __shfl_down(loss, off);
        if (tid == 0)
            out[0] = loss * (1.0f / (float)BB);
    }
}

extern "C" void kernel_launch(void* const* d_in, const int* in_sizes, int n_in,
                              void* d_out, int out_size, void* d_ws, size_t ws_size,
                              hipStream_t stream) {
    const float* depth = (const float*)d_in[0];
    const int*   xA    = (const int*)d_in[1];
    const int*   yA    = (const int*)d_in[2];
    const int*   xB    = (const int*)d_in[3];
    const int*   yB    = (const int*)d_in[4];
    const int*   rel   = (const int*)d_in[5];
    float*       out   = (float*)d_out;
    float4*      ws    = (float4*)d_ws;   // GRID*16 B = 16 KiB

    rdl_partial<<<GRID, TPB, 0, stream>>>(depth, xA, yA, xB, yB, rel, ws);
    rdl_final<<<1, TPB, 0, stream>>>(ws, out);
}